// Round 17
// baseline (684.120 us; speedup 1.0000x reference)
//
#include <hip/hip_runtime.h>
#include <math.h>

#define NROW 1024
#define INF_BITS 0x7F800000u
#define WINDOW   4.0e-3f     // > 2*max |d2_f32 - d2_f64| (bound ~8e-4)
#define CLAMP_EPS 1e-12f

typedef float nf4 __attribute__((ext_vector_type(4)));

__device__ __forceinline__ unsigned long long ull_min(unsigned long long a, unsigned long long b) {
    return a < b ? a : b;
}
__device__ __forceinline__ unsigned umax2(unsigned a, unsigned b) { return a > b ? a : b; }

// Per-row min/max of finite keys -> wave-reduced
#define ROW_MINMAX(K, MN, MX)                                                           \
    {                                                                                   \
        MN = 0xFFFFFFFFu; MX = 0u;                                                      \
        _Pragma("unroll")                                                               \
        for (int tt = 0; tt < 16; ++tt) {                                               \
            const unsigned kk_ = K[tt];                                                 \
            MN = kk_ < MN ? kk_ : MN;                                                   \
            const unsigned kf_ = (kk_ < INF_BITS) ? kk_ : 0u;                           \
            MX = kf_ > MX ? kf_ : MX;                                                   \
        }                                                                               \
        _Pragma("unroll")                                                               \
        for (int d = 1; d < 64; d <<= 1) {                                              \
            const unsigned omn = (unsigned)__shfl_xor((int)MN, d);                      \
            const unsigned omx = (unsigned)__shfl_xor((int)MX, d);                      \
            MN = omn < MN ? omn : MN;                                                   \
            MX = omx > MX ? omx : MX;                                                   \
        }                                                                               \
    }

// One bisection step for one row (stable when hi-lo<=1)
#define BISECT_STEP(K, LO, HI)                                                          \
    {                                                                                   \
        const unsigned mid_ = LO + ((HI - LO) >> 1);                                    \
        int cnt_ = 0;                                                                   \
        _Pragma("unroll")                                                               \
        for (int tt = 0; tt < 16; ++tt)                                                 \
            cnt_ += __popcll(__ballot(K[tt] < mid_));                                   \
        if (cnt_ >= 16) HI = mid_; else LO = mid_;                                      \
    }

// ---------------------------------------------------------------------------
// Boundary resolution for one row given V = 16th smallest f32 key.
// Fast path: no f32 tie ambiguity AND WINDOW gap -> f32 selection == f64's.
// Rare path: candidates one-per-lane, exact f64 rescore from nodes,
// (f64 bits, j) lowest-first extraction — jax top_k tie semantics.
// Uses lane, nbase, rowc, sqr64 from enclosing scope.
// ---------------------------------------------------------------------------
#define RESOLVE_ROW(K, V, RLOC, SELOUT)                                                 \
    {                                                                                   \
        const float Vw = __uint_as_float(V) + WINDOW;                                   \
        int cS = 0, nE = 0, cW = 0;                                                     \
        unsigned ltm = 0u, eqm = 0u, cm = 0u;                                           \
        _Pragma("unroll")                                                               \
        for (int tt = 0; tt < 16; ++tt) {                                               \
            const unsigned kk_ = K[tt];                                                 \
            const bool l_ = kk_ < (V);                                                  \
            const bool e_ = kk_ == (V);                                                 \
            const bool c_ = __uint_as_float(kk_) <= Vw;                                 \
            cS += __popcll(__ballot(l_));                                               \
            nE += __popcll(__ballot(e_));                                               \
            cW += __popcll(__ballot(c_));                                               \
            ltm |= (l_ ? 1u : 0u) << tt;                                                \
            eqm |= (e_ ? 1u : 0u) << tt;                                                \
            cm  |= (c_ ? 1u : 0u) << tt;                                                \
        }                                                                               \
        if (cS + nE == 16 && cW == 16) {                                                \
            SELOUT = ltm | eqm;                                                         \
        } else {                                                                        \
            int myj = -1;                                                               \
            {                                                                           \
                int cum = 0;                                                            \
                _Pragma("unroll")                                                       \
                for (int tt = 0; tt < 16; ++tt) {                                       \
                    const unsigned long long bm = __ballot((cm >> tt) & 1u);            \
                    const int pc = __popcll(bm);                                        \
                    if (myj < 0 && lane >= cum && lane < cum + pc) {                    \
                        unsigned long long mm = bm;                                     \
                        for (int z = lane - cum; z > 0; --z) mm &= mm - 1ull;           \
                        myj = tt * 64 + (__ffsll((unsigned long long)mm) - 1);          \
                    }                                                                   \
                    cum += pc;                                                          \
                }                                                                       \
            }                                                                           \
            unsigned long long dbits = ~0ull;                                           \
            if (myj >= 0) {                                                             \
                const float4* cp = (const float4*)(nbase + (size_t)myj * 64);           \
                double sq_ = 0.0, dt_ = 0.0;                                            \
                _Pragma("unroll")                                                       \
                for (int f = 0; f < 8; ++f) {                                           \
                    const float4 v = cp[f];                                             \
                    const float4 a = rowc[(RLOC) * 8 + f];                              \
                    sq_ = fma((double)v.x, (double)v.x, sq_);                           \
                    sq_ = fma((double)v.y, (double)v.y, sq_);                           \
                    sq_ = fma((double)v.z, (double)v.z, sq_);                           \
                    sq_ = fma((double)v.w, (double)v.w, sq_);                           \
                    dt_ = fma((double)v.x, (double)a.x, dt_);                           \
                    dt_ = fma((double)v.y, (double)a.y, dt_);                           \
                    dt_ = fma((double)v.z, (double)a.z, dt_);                           \
                    dt_ = fma((double)v.w, (double)a.w, dt_);                           \
                }                                                                       \
                double d64 = fma(-2.0, dt_, sqr64[RLOC] + sq_);                         \
                d64 = fmax(d64, (double)CLAMP_EPS);                                     \
                dbits = (unsigned long long)__double_as_longlong(d64);                  \
            }                                                                           \
            unsigned selb = 0u;                                                         \
            bool act = (myj >= 0);                                                      \
            for (int round = 0; round < 16; ++round) {                                  \
                unsigned long long best = act ? dbits : ~0ull;                          \
                _Pragma("unroll")                                                       \
                for (int d = 1; d < 64; d <<= 1)                                        \
                    best = ull_min(best,                                                \
                        (unsigned long long)__shfl_xor((long long)best, d));            \
                int pj = (act && dbits == best) ? myj : 0x7FFFFFFF;                     \
                _Pragma("unroll")                                                       \
                for (int d = 1; d < 64; d <<= 1) {                                      \
                    const int o = __shfl_xor(pj, d);                                    \
                    pj = o < pj ? o : pj;                                               \
                }                                                                       \
                if (myj == pj) act = false;                                             \
                if (lane == (pj & 63)) selb |= 1u << (pj >> 6);                         \
            }                                                                           \
            SELOUT = selb;                                                              \
        }                                                                               \
    }

// ---------------------------------------------------------------------------
// precompute: transpose coords into [b][f][j] float4 planes (coalesced main-
// loop loads) + per-column squared norms (identical fma order -> bitwise-
// identical keys). XCD-swizzled so batch b's panel is written by (and cached
// in the L2 of) the same XCD that later reads it: XCD x <-> batches [8x,8x+8).
// ---------------------------------------------------------------------------
__global__ __launch_bounds__(256) void transpose_norm_kernel(
    const float* __restrict__ nodes, float4* __restrict__ wsT,
    float* __restrict__ sqc)
{
    // 256 hw blocks; logical block l covers batch l/4. Map so l/32 == hw%8 (XCD id).
    const int w = blockIdx.x;
    const int l = (w & 7) * 32 + (w >> 3);
    const int g = l * 256 + threadIdx.x;             // 0..65535 = b*1024 + j
    const int b = g >> 10, j = g & 1023;
    const float4* cp = (const float4*)(nodes + (size_t)g * 64);
    float4 c[8];
    float s = 0.f;
#pragma unroll
    for (int f = 0; f < 8; ++f) {
        c[f] = cp[f];
        s = fmaf(c[f].x, c[f].x, s); s = fmaf(c[f].y, c[f].y, s);
        s = fmaf(c[f].z, c[f].z, s); s = fmaf(c[f].w, c[f].w, s);
    }
#pragma unroll
    for (int f = 0; f < 8; ++f)
        wsT[(((size_t)b * 8 + f) << 10) + j] = c[f];   // coalesced: consecutive j
    sqc[g] = s;
}

// ---------------------------------------------------------------------------
// persistent-wave edge kernel: 2048 one-wave blocks (8/CU), each handling 8
// row-groups of ONE batch (b constant per block; same XCD<->batch map as the
// transpose writer). Per-iteration body is byte-for-byte the r11 champion.
// Cross-iteration: NT stores drain while next iteration's staging/loads issue.
// ---------------------------------------------------------------------------
template <int USE_WS>
__global__ __launch_bounds__(64) void edge_knn_kernel(
    const float* __restrict__ nodes,
    const int*   __restrict__ mask,
    const float4* __restrict__ wsT,
    const float* __restrict__ sqcw,
    float*       __restrict__ out)
{
    const int lane = threadIdx.x;              // 64-thread blocks = 1 wave
    const int w    = blockIdx.x;               // 2048 blocks, round-robin XCDs
    const int xcd  = w & 7;
    const int q    = w >> 3;                   // 0..255 within XCD
    // batch is constant per block: q*8..q*8+7 stay within one 256-group batch
    const int b    = xcd * 8 + (q >> 5);
    const int gbase = (q & 31) * 8;            // first row-group within batch

    const int* maskb = mask + b * NROW;
    float* edges = out + (size_t)b * NROW * NROW;
    float* adjm  = out + (size_t)64 * NROW * NROW + (size_t)b * NROW * NROW;
    const float* nbase = nodes + (size_t)b * NROW * 64;
    const float4* tbase = USE_WS ? (wsT + ((size_t)b * 8 << 10)) : (const float4*)nullptr;
    const float*  sqb   = USE_WS ? (sqcw + (size_t)b * NROW) : (const float*)nullptr;

    // column validity bits (batch-constant): bit tt <-> column j = tt*64 + lane
    unsigned mb = 0u;
#pragma unroll
    for (int tt = 0; tt < 16; ++tt)
        mb |= (maskb[tt * 64 + lane] != 0 ? 1u : 0u) << tt;

    __shared__ float4 rowc[4 * 8];      // 512 B: current group's 4 row vectors
    __shared__ float  sqr32s[4];
    __shared__ double sqr64[4];

    for (int it = 0; it < 8; ++it) {
        const int rowbase = (gbase + it) * 4;
        const int row0 = rowbase;

        // ---- fast path: all 4 rows masked -> zero-fill (d_out is poisoned)
        const int anyv = maskb[rowbase] | maskb[rowbase + 1]
                       | maskb[rowbase + 2] | maskb[rowbase + 3];
        if (!anyv) {
            const nf4 z = {0.f, 0.f, 0.f, 0.f};
#pragma unroll
            for (int r = 0; r < 4; ++r) {
                nf4* e4 = reinterpret_cast<nf4*>(edges + (size_t)(rowbase + r) * NROW);
                nf4* a4 = reinterpret_cast<nf4*>(adjm  + (size_t)(rowbase + r) * NROW);
#pragma unroll
                for (int p = 0; p < 4; ++p) {
                    __builtin_nontemporal_store(z, e4 + p * 64 + lane);
                    __builtin_nontemporal_store(z, a4 + p * 64 + lane);
                }
            }
            continue;
        }

        // ---- stage this group's 4 row vectors (1-wave barrier: cheap)
        if (lane < 32) {
            const int r = lane >> 3, f = lane & 7;
            rowc[lane] = ((const float4*)(nbase + (size_t)(rowbase + r) * 64))[f];
        }
        __syncthreads();
        if (lane < 4) {
            double s = 0.0;
#pragma unroll
            for (int f = 0; f < 8; ++f) {
                const float4 v = rowc[lane * 8 + f];
                s = fma((double)v.x, (double)v.x, s);
                s = fma((double)v.y, (double)v.y, s);
                s = fma((double)v.z, (double)v.z, s);
                s = fma((double)v.w, (double)v.w, s);
            }
            sqr64[lane] = s;
            sqr32s[lane] = (float)s;
        }
        __syncthreads();

        const bool rv0 = maskb[row0 + 0] != 0;
        const bool rv1 = maskb[row0 + 1] != 0;
        const bool rv2 = maskb[row0 + 2] != 0;
        const bool rv3 = maskb[row0 + 3] != 0;
        const float sqr0 = sqr32s[0], sqr1 = sqr32s[1];
        const float sqr2 = sqr32s[2], sqr3 = sqr32s[3];

        unsigned k0[16], k1[16], k2[16], k3[16];

        // ---- main loop: barrier-free; coalesced transposed loads (USE_WS)
#pragma unroll
        for (int tt = 0; tt < 16; ++tt) {
            if (__ballot((mb >> tt) & 1u) == 0ull) {   // wave-uniform skip
                k0[tt] = INF_BITS; k1[tt] = INF_BITS;
                k2[tt] = INF_BITS; k3[tt] = INF_BITS;
                continue;
            }
            const int j = tt * 64 + lane;
            float4 c[8];
            float sA;
            if (USE_WS) {
#pragma unroll
                for (int f = 0; f < 8; ++f) c[f] = tbase[(f << 10) + j];
                sA = sqb[j];                           // coalesced dword, L2-hot
            } else {
                const float4* cp = (const float4*)(nbase + (size_t)j * 64);
#pragma unroll
                for (int f = 0; f < 8; ++f) c[f] = cp[f];
                sA = 0.f;
#pragma unroll
                for (int f = 0; f < 8; ++f) {
                    sA = fmaf(c[f].x, c[f].x, sA); sA = fmaf(c[f].y, c[f].y, sA);
                    sA = fmaf(c[f].z, c[f].z, sA); sA = fmaf(c[f].w, c[f].w, sA);
                }
            }

            float d0 = 0.f, d1 = 0.f, d2 = 0.f, d3 = 0.f;
#pragma unroll
            for (int f = 0; f < 8; ++f) {
                const float4 v  = c[f];
                const float4 a0 = rowc[0 * 8 + f];   // wave-uniform broadcasts
                const float4 a1 = rowc[1 * 8 + f];
                const float4 a2 = rowc[2 * 8 + f];
                const float4 a3 = rowc[3 * 8 + f];
                d0 = fmaf(v.x, a0.x, d0); d0 = fmaf(v.y, a0.y, d0);
                d0 = fmaf(v.z, a0.z, d0); d0 = fmaf(v.w, a0.w, d0);
                d1 = fmaf(v.x, a1.x, d1); d1 = fmaf(v.y, a1.y, d1);
                d1 = fmaf(v.z, a1.z, d1); d1 = fmaf(v.w, a1.w, d1);
                d2 = fmaf(v.x, a2.x, d2); d2 = fmaf(v.y, a2.y, d2);
                d2 = fmaf(v.z, a2.z, d2); d2 = fmaf(v.w, a2.w, d2);
                d3 = fmaf(v.x, a3.x, d3); d3 = fmaf(v.y, a3.y, d3);
                d3 = fmaf(v.z, a3.z, d3); d3 = fmaf(v.w, a3.w, d3);
            }

            const bool cv = (mb >> tt) & 1u;
            float e_;
            e_ = fmaxf(fmaf(-2.f, d0, sqr0 + sA), CLAMP_EPS);
            k0[tt] = (cv && j != row0 + 0) ? __float_as_uint(e_) : INF_BITS;
            e_ = fmaxf(fmaf(-2.f, d1, sqr1 + sA), CLAMP_EPS);
            k1[tt] = (cv && j != row0 + 1) ? __float_as_uint(e_) : INF_BITS;
            e_ = fmaxf(fmaf(-2.f, d2, sqr2 + sA), CLAMP_EPS);
            k2[tt] = (cv && j != row0 + 2) ? __float_as_uint(e_) : INF_BITS;
            e_ = fmaxf(fmaf(-2.f, d3, sqr3 + sA), CLAMP_EPS);
            k3[tt] = (cv && j != row0 + 3) ? __float_as_uint(e_) : INF_BITS;
        }

        // ---- joint 4-row bisection (4 independent ballot chains / iteration)
        unsigned mn0, mx0, mn1, mx1, mn2, mx2, mn3, mx3;
        ROW_MINMAX(k0, mn0, mx0);
        ROW_MINMAX(k1, mn1, mx1);
        ROW_MINMAX(k2, mn2, mx2);
        ROW_MINMAX(k3, mn3, mx3);

        unsigned lo0 = mn0, hi0 = mx0 + 1u;
        unsigned lo1 = mn1, hi1 = mx1 + 1u;
        unsigned lo2 = mn2, hi2 = mx2 + 1u;
        unsigned lo3 = mn3, hi3 = mx3 + 1u;
        if (!rv0) { lo0 = 0u; hi0 = 1u; }
        if (!rv1) { lo1 = 0u; hi1 = 1u; }
        if (!rv2) { lo2 = 0u; hi2 = 1u; }
        if (!rv3) { lo3 = 0u; hi3 = 1u; }

        for (;;) {
            const unsigned dm = umax2(umax2(hi0 - lo0, hi1 - lo1),
                                      umax2(hi2 - lo2, hi3 - lo3));
            if (dm <= 1u) break;
            BISECT_STEP(k0, lo0, hi0);
            BISECT_STEP(k1, lo1, hi1);
            BISECT_STEP(k2, lo2, hi2);
            BISECT_STEP(k3, lo3, hi3);
        }

        // ---- boundary resolution (wave-uniform per-row branches)
        unsigned sel0 = 0u, sel1 = 0u, sel2 = 0u, sel3 = 0u;
        if (rv0) RESOLVE_ROW(k0, lo0, 0, sel0);
        if (rv1) RESOLVE_ROW(k1, lo1, 1, sel1);
        if (rv2) RESOLVE_ROW(k2, lo2, 2, sel2);
        if (rv3) RESOLVE_ROW(k3, lo3, 3, sel3);

        // ---- dense output (coalesced NT dword streams; bypass L2 so the
        // 537MB write stream doesn't evict the XCD-local wsT panels — r16 A/B)
#pragma unroll
        for (int tt = 0; tt < 16; ++tt) {
            const int j = tt * 64 + lane;
            {
                const bool s = (sel0 >> tt) & 1u;
                __builtin_nontemporal_store(s ? sqrtf(__uint_as_float(k0[tt])) : 0.f,
                                            edges + (size_t)(row0 + 0) * NROW + j);
                __builtin_nontemporal_store(s ? 1.f : 0.f,
                                            adjm + (size_t)(row0 + 0) * NROW + j);
            }
            {
                const bool s = (sel1 >> tt) & 1u;
                __builtin_nontemporal_store(s ? sqrtf(__uint_as_float(k1[tt])) : 0.f,
                                            edges + (size_t)(row0 + 1) * NROW + j);
                __builtin_nontemporal_store(s ? 1.f : 0.f,
                                            adjm + (size_t)(row0 + 1) * NROW + j);
            }
            {
                const bool s = (sel2 >> tt) & 1u;
                __builtin_nontemporal_store(s ? sqrtf(__uint_as_float(k2[tt])) : 0.f,
                                            edges + (size_t)(row0 + 2) * NROW + j);
                __builtin_nontemporal_store(s ? 1.f : 0.f,
                                            adjm + (size_t)(row0 + 2) * NROW + j);
            }
            {
                const bool s = (sel3 >> tt) & 1u;
                __builtin_nontemporal_store(s ? sqrtf(__uint_as_float(k3[tt])) : 0.f,
                                            edges + (size_t)(row0 + 3) * NROW + j);
                __builtin_nontemporal_store(s ? 1.f : 0.f,
                                            adjm + (size_t)(row0 + 3) * NROW + j);
            }
        }
    }
}

extern "C" void kernel_launch(void* const* d_in, const int* in_sizes, int n_in,
                              void* d_out, int out_size, void* d_ws, size_t ws_size,
                              hipStream_t stream)
{
    const float* nodes = (const float*)d_in[0];
    const int*   mask  = (const int*)d_in[1];
    float* out = (float*)d_out;

    dim3 grid(2048);       // persistent: 8 one-wave blocks per CU, 8 groups each
    dim3 block(64);

    const size_t wsT_f4 = (size_t)64 * 8 * 1024;              // 8 MB of float4
    const size_t need   = wsT_f4 * sizeof(float4) + (size_t)64 * NROW * sizeof(float);
    const bool   use_ws = ws_size >= need;

    if (use_ws) {
        float4* wsT = (float4*)d_ws;
        float*  sqc = (float*)((char*)d_ws + wsT_f4 * sizeof(float4));
        hipLaunchKernelGGL(transpose_norm_kernel, dim3(64 * NROW / 256), dim3(256), 0, stream,
                           nodes, wsT, sqc);
        hipLaunchKernelGGL((edge_knn_kernel<1>), grid, block, 0, stream,
                           nodes, mask, (const float4*)wsT, (const float*)sqc, out);
    } else {
        hipLaunchKernelGGL((edge_knn_kernel<0>), grid, block, 0, stream,
                           nodes, mask, (const float4*)nullptr, (const float*)nullptr, out);
    }
}

// Round 18
// 351.000 us; speedup vs baseline: 1.9491x; 1.9491x over previous
//
#include <hip/hip_runtime.h>
#include <math.h>

#define NROW 1024
#define INF_BITS 0x7F800000u
#define WINDOW   4.0e-3f     // > 2*max |d2_f32 - d2_f64| (bound ~8e-4)
#define CLAMP_EPS 1e-12f

typedef float nf4 __attribute__((ext_vector_type(4)));

__device__ __forceinline__ unsigned long long ull_min(unsigned long long a, unsigned long long b) {
    return a < b ? a : b;
}
__device__ __forceinline__ unsigned umax2(unsigned a, unsigned b) { return a > b ? a : b; }

// Per-row min/max of finite keys -> wave-reduced
#define ROW_MINMAX(K, MN, MX)                                                           \
    {                                                                                   \
        MN = 0xFFFFFFFFu; MX = 0u;                                                      \
        _Pragma("unroll")                                                               \
        for (int tt = 0; tt < 16; ++tt) {                                               \
            const unsigned kk_ = K[tt];                                                 \
            MN = kk_ < MN ? kk_ : MN;                                                   \
            const unsigned kf_ = (kk_ < INF_BITS) ? kk_ : 0u;                           \
            MX = kf_ > MX ? kf_ : MX;                                                   \
        }                                                                               \
        _Pragma("unroll")                                                               \
        for (int d = 1; d < 64; d <<= 1) {                                              \
            const unsigned omn = (unsigned)__shfl_xor((int)MN, d);                      \
            const unsigned omx = (unsigned)__shfl_xor((int)MX, d);                      \
            MN = omn < MN ? omn : MN;                                                   \
            MX = omx > MX ? omx : MX;                                                   \
        }                                                                               \
    }

// One bisection step for one row (stable when hi-lo<=1)
#define BISECT_STEP(K, LO, HI)                                                          \
    {                                                                                   \
        const unsigned mid_ = LO + ((HI - LO) >> 1);                                    \
        int cnt_ = 0;                                                                   \
        _Pragma("unroll")                                                               \
        for (int tt = 0; tt < 16; ++tt)                                                 \
            cnt_ += __popcll(__ballot(K[tt] < mid_));                                   \
        if (cnt_ >= 16) HI = mid_; else LO = mid_;                                      \
    }

// ---------------------------------------------------------------------------
// Boundary resolution for one row given V = 16th smallest f32 key.
// Fast path: no f32 tie ambiguity AND WINDOW gap -> f32 selection == f64's.
// Rare path: candidates one-per-lane, exact f64 rescore from nodes,
// (f64 bits, j) lowest-first extraction — jax top_k tie semantics.
// Uses lane, nbase, rowc, sqr64 from enclosing scope.
// ---------------------------------------------------------------------------
#define RESOLVE_ROW(K, V, RLOC, SELOUT)                                                 \
    {                                                                                   \
        const float Vw = __uint_as_float(V) + WINDOW;                                   \
        int cS = 0, nE = 0, cW = 0;                                                     \
        unsigned ltm = 0u, eqm = 0u, cm = 0u;                                           \
        _Pragma("unroll")                                                               \
        for (int tt = 0; tt < 16; ++tt) {                                               \
            const unsigned kk_ = K[tt];                                                 \
            const bool l_ = kk_ < (V);                                                  \
            const bool e_ = kk_ == (V);                                                 \
            const bool c_ = __uint_as_float(kk_) <= Vw;                                 \
            cS += __popcll(__ballot(l_));                                               \
            nE += __popcll(__ballot(e_));                                               \
            cW += __popcll(__ballot(c_));                                               \
            ltm |= (l_ ? 1u : 0u) << tt;                                                \
            eqm |= (e_ ? 1u : 0u) << tt;                                                \
            cm  |= (c_ ? 1u : 0u) << tt;                                                \
        }                                                                               \
        if (cS + nE == 16 && cW == 16) {                                                \
            SELOUT = ltm | eqm;                                                         \
        } else {                                                                        \
            int myj = -1;                                                               \
            {                                                                           \
                int cum = 0;                                                            \
                _Pragma("unroll")                                                       \
                for (int tt = 0; tt < 16; ++tt) {                                       \
                    const unsigned long long bm = __ballot((cm >> tt) & 1u);            \
                    const int pc = __popcll(bm);                                        \
                    if (myj < 0 && lane >= cum && lane < cum + pc) {                    \
                        unsigned long long mm = bm;                                     \
                        for (int z = lane - cum; z > 0; --z) mm &= mm - 1ull;           \
                        myj = tt * 64 + (__ffsll((unsigned long long)mm) - 1);          \
                    }                                                                   \
                    cum += pc;                                                          \
                }                                                                       \
            }                                                                           \
            unsigned long long dbits = ~0ull;                                           \
            if (myj >= 0) {                                                             \
                const float4* cp = (const float4*)(nbase + (size_t)myj * 64);           \
                double sq_ = 0.0, dt_ = 0.0;                                            \
                _Pragma("unroll")                                                       \
                for (int f = 0; f < 8; ++f) {                                           \
                    const float4 v = cp[f];                                             \
                    const float4 a = rowc[(RLOC) * 8 + f];                              \
                    sq_ = fma((double)v.x, (double)v.x, sq_);                           \
                    sq_ = fma((double)v.y, (double)v.y, sq_);                           \
                    sq_ = fma((double)v.z, (double)v.z, sq_);                           \
                    sq_ = fma((double)v.w, (double)v.w, sq_);                           \
                    dt_ = fma((double)v.x, (double)a.x, dt_);                           \
                    dt_ = fma((double)v.y, (double)a.y, dt_);                           \
                    dt_ = fma((double)v.z, (double)a.z, dt_);                           \
                    dt_ = fma((double)v.w, (double)a.w, dt_);                           \
                }                                                                       \
                double d64 = fma(-2.0, dt_, sqr64[RLOC] + sq_);                         \
                d64 = fmax(d64, (double)CLAMP_EPS);                                     \
                dbits = (unsigned long long)__double_as_longlong(d64);                  \
            }                                                                           \
            unsigned selb = 0u;                                                         \
            bool act = (myj >= 0);                                                      \
            for (int round = 0; round < 16; ++round) {                                  \
                unsigned long long best = act ? dbits : ~0ull;                          \
                _Pragma("unroll")                                                       \
                for (int d = 1; d < 64; d <<= 1)                                        \
                    best = ull_min(best,                                                \
                        (unsigned long long)__shfl_xor((long long)best, d));            \
                int pj = (act && dbits == best) ? myj : 0x7FFFFFFF;                     \
                _Pragma("unroll")                                                       \
                for (int d = 1; d < 64; d <<= 1) {                                      \
                    const int o = __shfl_xor(pj, d);                                    \
                    pj = o < pj ? o : pj;                                               \
                }                                                                       \
                if (myj == pj) act = false;                                             \
                if (lane == (pj & 63)) selb |= 1u << (pj >> 6);                         \
            }                                                                           \
            SELOUT = selb;                                                              \
        }                                                                               \
    }

// 4 FMAs of one row's rowc float4 against column vector v
#define DOT1(V, A, D)                                                                   \
    D = fmaf(V.x, A.x, D); D = fmaf(V.y, A.y, D);                                       \
    D = fmaf(V.z, A.z, D); D = fmaf(V.w, A.w, D);

// key formation for one row
#define MK(K, D, SQR, RIDX)                                                             \
    {                                                                                   \
        const float e_ = fmaxf(fmaf(-2.f, D, (SQR) + sA), CLAMP_EPS);                   \
        K[tt] = (cv && j != row0 + (RIDX)) ? __float_as_uint(e_) : INF_BITS;            \
    }

// NT store of one row's (edge, adj) at column j
#define ST(K, SEL, RIDX)                                                                \
    {                                                                                   \
        const bool s = ((SEL) >> tt) & 1u;                                              \
        __builtin_nontemporal_store(s ? sqrtf(__uint_as_float(K[tt])) : 0.f,            \
                                    edges + (size_t)(row0 + (RIDX)) * NROW + j);        \
        __builtin_nontemporal_store(s ? 1.f : 0.f,                                      \
                                    adjm + (size_t)(row0 + (RIDX)) * NROW + j);         \
    }

// ---------------------------------------------------------------------------
// precompute: transpose coords into [b][f][j] float4 planes (coalesced main-
// loop loads) + per-column squared norms (identical fma order -> bitwise-
// identical keys). XCD-swizzled so batch b's panel is written by (and cached
// in the L2 of) the same XCD that later reads it: XCD x <-> batches [8x,8x+8).
// ---------------------------------------------------------------------------
__global__ __launch_bounds__(256) void transpose_norm_kernel(
    const float* __restrict__ nodes, float4* __restrict__ wsT,
    float* __restrict__ sqc)
{
    // 256 hw blocks; logical block l covers batch l/4. Map so l/32 == hw%8 (XCD id).
    const int w = blockIdx.x;
    const int l = (w & 7) * 32 + (w >> 3);
    const int g = l * 256 + threadIdx.x;             // 0..65535 = b*1024 + j
    const int b = g >> 10, j = g & 1023;
    const float4* cp = (const float4*)(nodes + (size_t)g * 64);
    float4 c[8];
    float s = 0.f;
#pragma unroll
    for (int f = 0; f < 8; ++f) {
        c[f] = cp[f];
        s = fmaf(c[f].x, c[f].x, s); s = fmaf(c[f].y, c[f].y, s);
        s = fmaf(c[f].z, c[f].z, s); s = fmaf(c[f].w, c[f].w, s);
    }
#pragma unroll
    for (int f = 0; f < 8; ++f)
        wsT[(((size_t)b * 8 + f) << 10) + j] = c[f];   // coalesced: consecutive j
    sqc[g] = s;
}

// ---------------------------------------------------------------------------
// edge kernel: r11 champion frame, 8 rows per wave (halves per-row panel
// traffic: each wave reads the 128KB wsT panel once for 8 output rows).
// ---------------------------------------------------------------------------
template <int USE_WS>
__global__ __launch_bounds__(64) void edge_knn_kernel(
    const float* __restrict__ nodes,
    const int*   __restrict__ mask,
    const float4* __restrict__ wsT,
    const float* __restrict__ sqcw,
    float*       __restrict__ out)
{
    const int lane = threadIdx.x;              // 64-thread blocks = 1 wave
    // XCD-aware bijective swizzle (nwg=8192, 8192%8==0): XCD x gets logical
    // blocks [x*1024,(x+1)*1024) = batches [8x,8x+8) -> per-XCD wsT working
    // set 1MB, L2-resident (matches transpose kernel's write mapping).
    const int blk  = (int)((blockIdx.x & 7) * 1024 + (blockIdx.x >> 3));
    const int b    = blk >> 7;                 // 128 blocks per batch
    const int rowbase = (blk & 127) * 8;       // 8 rows per block

    const int* maskb = mask + b * NROW;
    float* edges = out + (size_t)b * NROW * NROW;
    float* adjm  = out + (size_t)64 * NROW * NROW + (size_t)b * NROW * NROW;

    // ---- fast path: all 8 rows masked -> zero-fill (d_out is poisoned)
    int anyv = 0;
#pragma unroll
    for (int r = 0; r < 8; ++r) anyv |= maskb[rowbase + r];
    if (!anyv) {
        const nf4 z = {0.f, 0.f, 0.f, 0.f};
#pragma unroll
        for (int r = 0; r < 8; ++r) {
            nf4* e4 = reinterpret_cast<nf4*>(edges + (size_t)(rowbase + r) * NROW);
            nf4* a4 = reinterpret_cast<nf4*>(adjm  + (size_t)(rowbase + r) * NROW);
#pragma unroll
            for (int p = 0; p < 4; ++p) {
                __builtin_nontemporal_store(z, e4 + p * 64 + lane);
                __builtin_nontemporal_store(z, a4 + p * 64 + lane);
            }
        }
        return;
    }

    __shared__ float4 rowc[8 * 8];      // 2 KB: this wave's 8 row coord vectors
    __shared__ float  sqr32s[8];
    __shared__ double sqr64[8];

    const float* nbase = nodes + (size_t)b * NROW * 64;

    {   // stage 8 rows x 8 float4 = 64 slots, one per lane
        const int r = lane >> 3, f = lane & 7;
        rowc[lane] = ((const float4*)(nbase + (size_t)(rowbase + r) * 64))[f];
    }
    __syncthreads();
    if (lane < 8) {
        double s = 0.0;
#pragma unroll
        for (int f = 0; f < 8; ++f) {
            const float4 v = rowc[lane * 8 + f];
            s = fma((double)v.x, (double)v.x, s);
            s = fma((double)v.y, (double)v.y, s);
            s = fma((double)v.z, (double)v.z, s);
            s = fma((double)v.w, (double)v.w, s);
        }
        sqr64[lane] = s;
        sqr32s[lane] = (float)s;
    }
    __syncthreads();

    // column validity bits: bit tt <-> column j = tt*64 + lane
    unsigned mb = 0u;
#pragma unroll
    for (int tt = 0; tt < 16; ++tt)
        mb |= (maskb[tt * 64 + lane] != 0 ? 1u : 0u) << tt;

    const int row0 = rowbase;
    const bool rv0 = maskb[row0 + 0] != 0;
    const bool rv1 = maskb[row0 + 1] != 0;
    const bool rv2 = maskb[row0 + 2] != 0;
    const bool rv3 = maskb[row0 + 3] != 0;
    const bool rv4 = maskb[row0 + 4] != 0;
    const bool rv5 = maskb[row0 + 5] != 0;
    const bool rv6 = maskb[row0 + 6] != 0;
    const bool rv7 = maskb[row0 + 7] != 0;
    const float sqr0 = sqr32s[0], sqr1 = sqr32s[1], sqr2 = sqr32s[2], sqr3 = sqr32s[3];
    const float sqr4 = sqr32s[4], sqr5 = sqr32s[5], sqr6 = sqr32s[6], sqr7 = sqr32s[7];

    unsigned k0[16], k1[16], k2[16], k3[16], k4[16], k5[16], k6[16], k7[16];

    // ---- main loop: barrier-free; coalesced transposed loads (USE_WS)
#pragma unroll
    for (int tt = 0; tt < 16; ++tt) {
        if (__ballot((mb >> tt) & 1u) == 0ull) {   // wave-uniform prefix-mask skip
            k0[tt] = INF_BITS; k1[tt] = INF_BITS; k2[tt] = INF_BITS; k3[tt] = INF_BITS;
            k4[tt] = INF_BITS; k5[tt] = INF_BITS; k6[tt] = INF_BITS; k7[tt] = INF_BITS;
            continue;
        }
        const int j = tt * 64 + lane;
        float4 c[8];
        float sA;
        if (USE_WS) {
            const float4* tbase = wsT + ((size_t)b * 8 << 10);
#pragma unroll
            for (int f = 0; f < 8; ++f) c[f] = tbase[(f << 10) + j];
            sA = sqcw[(size_t)b * NROW + j];       // coalesced dword, L2-hot
        } else {
            const float4* cp = (const float4*)(nbase + (size_t)j * 64);
#pragma unroll
            for (int f = 0; f < 8; ++f) c[f] = cp[f];
            sA = 0.f;
#pragma unroll
            for (int f = 0; f < 8; ++f) {
                sA = fmaf(c[f].x, c[f].x, sA); sA = fmaf(c[f].y, c[f].y, sA);
                sA = fmaf(c[f].z, c[f].z, sA); sA = fmaf(c[f].w, c[f].w, sA);
            }
        }

        float d0 = 0.f, d1 = 0.f, d2 = 0.f, d3 = 0.f;
        float d4 = 0.f, d5 = 0.f, d6 = 0.f, d7 = 0.f;
#pragma unroll
        for (int f = 0; f < 8; ++f) {
            const float4 v  = c[f];
            const float4 a0 = rowc[0 * 8 + f];   // wave-uniform broadcast reads
            const float4 a1 = rowc[1 * 8 + f];
            const float4 a2 = rowc[2 * 8 + f];
            const float4 a3 = rowc[3 * 8 + f];
            const float4 a4 = rowc[4 * 8 + f];
            const float4 a5 = rowc[5 * 8 + f];
            const float4 a6 = rowc[6 * 8 + f];
            const float4 a7 = rowc[7 * 8 + f];
            DOT1(v, a0, d0); DOT1(v, a1, d1); DOT1(v, a2, d2); DOT1(v, a3, d3);
            DOT1(v, a4, d4); DOT1(v, a5, d5); DOT1(v, a6, d6); DOT1(v, a7, d7);
        }

        const bool cv = (mb >> tt) & 1u;
        MK(k0, d0, sqr0, 0); MK(k1, d1, sqr1, 1); MK(k2, d2, sqr2, 2); MK(k3, d3, sqr3, 3);
        MK(k4, d4, sqr4, 4); MK(k5, d5, sqr5, 5); MK(k6, d6, sqr6, 6); MK(k7, d7, sqr7, 7);
    }

    // ---- joint 8-row bisection (8 independent ballot chains per iteration)
    unsigned mn0, mx0, mn1, mx1, mn2, mx2, mn3, mx3;
    unsigned mn4, mx4, mn5, mx5, mn6, mx6, mn7, mx7;
    ROW_MINMAX(k0, mn0, mx0); ROW_MINMAX(k1, mn1, mx1);
    ROW_MINMAX(k2, mn2, mx2); ROW_MINMAX(k3, mn3, mx3);
    ROW_MINMAX(k4, mn4, mx4); ROW_MINMAX(k5, mn5, mx5);
    ROW_MINMAX(k6, mn6, mx6); ROW_MINMAX(k7, mn7, mx7);

    unsigned lo0 = mn0, hi0 = mx0 + 1u, lo1 = mn1, hi1 = mx1 + 1u;
    unsigned lo2 = mn2, hi2 = mx2 + 1u, lo3 = mn3, hi3 = mx3 + 1u;
    unsigned lo4 = mn4, hi4 = mx4 + 1u, lo5 = mn5, hi5 = mx5 + 1u;
    unsigned lo6 = mn6, hi6 = mx6 + 1u, lo7 = mn7, hi7 = mx7 + 1u;
    if (!rv0) { lo0 = 0u; hi0 = 1u; }
    if (!rv1) { lo1 = 0u; hi1 = 1u; }
    if (!rv2) { lo2 = 0u; hi2 = 1u; }
    if (!rv3) { lo3 = 0u; hi3 = 1u; }
    if (!rv4) { lo4 = 0u; hi4 = 1u; }
    if (!rv5) { lo5 = 0u; hi5 = 1u; }
    if (!rv6) { lo6 = 0u; hi6 = 1u; }
    if (!rv7) { lo7 = 0u; hi7 = 1u; }

    for (;;) {
        const unsigned dm = umax2(
            umax2(umax2(hi0 - lo0, hi1 - lo1), umax2(hi2 - lo2, hi3 - lo3)),
            umax2(umax2(hi4 - lo4, hi5 - lo5), umax2(hi6 - lo6, hi7 - lo7)));
        if (dm <= 1u) break;
        BISECT_STEP(k0, lo0, hi0); BISECT_STEP(k1, lo1, hi1);
        BISECT_STEP(k2, lo2, hi2); BISECT_STEP(k3, lo3, hi3);
        BISECT_STEP(k4, lo4, hi4); BISECT_STEP(k5, lo5, hi5);
        BISECT_STEP(k6, lo6, hi6); BISECT_STEP(k7, lo7, hi7);
    }

    // ---- boundary resolution (wave-uniform per-row branches)
    unsigned sel0 = 0u, sel1 = 0u, sel2 = 0u, sel3 = 0u;
    unsigned sel4 = 0u, sel5 = 0u, sel6 = 0u, sel7 = 0u;
    if (rv0) RESOLVE_ROW(k0, lo0, 0, sel0);
    if (rv1) RESOLVE_ROW(k1, lo1, 1, sel1);
    if (rv2) RESOLVE_ROW(k2, lo2, 2, sel2);
    if (rv3) RESOLVE_ROW(k3, lo3, 3, sel3);
    if (rv4) RESOLVE_ROW(k4, lo4, 4, sel4);
    if (rv5) RESOLVE_ROW(k5, lo5, 5, sel5);
    if (rv6) RESOLVE_ROW(k6, lo6, 6, sel6);
    if (rv7) RESOLVE_ROW(k7, lo7, 7, sel7);

    // ---- dense output (coalesced NT dword streams; bypass L2 so the 537MB
    // write stream doesn't evict the XCD-local wsT panels — r16 A/B evidence)
#pragma unroll
    for (int tt = 0; tt < 16; ++tt) {
        const int j = tt * 64 + lane;
        ST(k0, sel0, 0); ST(k1, sel1, 1); ST(k2, sel2, 2); ST(k3, sel3, 3);
        ST(k4, sel4, 4); ST(k5, sel5, 5); ST(k6, sel6, 6); ST(k7, sel7, 7);
    }
}

extern "C" void kernel_launch(void* const* d_in, const int* in_sizes, int n_in,
                              void* d_out, int out_size, void* d_ws, size_t ws_size,
                              hipStream_t stream)
{
    const float* nodes = (const float*)d_in[0];
    const int*   mask  = (const int*)d_in[1];
    float* out = (float*)d_out;

    dim3 grid(64 * 128);   // 64 batches x 128 blocks (8 rows each, 1 wave/block)
    dim3 block(64);

    const size_t wsT_f4 = (size_t)64 * 8 * 1024;              // 8 MB of float4
    const size_t need   = wsT_f4 * sizeof(float4) + (size_t)64 * NROW * sizeof(float);
    const bool   use_ws = ws_size >= need;

    if (use_ws) {
        float4* wsT = (float4*)d_ws;
        float*  sqc = (float*)((char*)d_ws + wsT_f4 * sizeof(float4));
        hipLaunchKernelGGL(transpose_norm_kernel, dim3(64 * NROW / 256), dim3(256), 0, stream,
                           nodes, wsT, sqc);
        hipLaunchKernelGGL((edge_knn_kernel<1>), grid, block, 0, stream,
                           nodes, mask, (const float4*)wsT, (const float*)sqc, out);
    } else {
        hipLaunchKernelGGL((edge_knn_kernel<0>), grid, block, 0, stream,
                           nodes, mask, (const float4*)nullptr, (const float*)nullptr, out);
    }
}

// Round 19
// 244.249 us; speedup vs baseline: 2.8009x; 1.4371x over previous
//
#include <hip/hip_runtime.h>
#include <math.h>

#define NROW 1024
#define INF_BITS 0x7F800000u
#define WINDOW   4.0e-3f     // > 2*max |d2_f32 - d2_f64| (bound ~8e-4)
#define CLAMP_EPS 1e-12f

typedef float nf4 __attribute__((ext_vector_type(4)));

__device__ __forceinline__ unsigned long long ull_min(unsigned long long a, unsigned long long b) {
    return a < b ? a : b;
}
__device__ __forceinline__ unsigned umax2(unsigned a, unsigned b) { return a > b ? a : b; }

// Per-row min/max of finite keys -> wave-reduced
#define ROW_MINMAX(K, MN, MX)                                                           \
    {                                                                                   \
        MN = 0xFFFFFFFFu; MX = 0u;                                                      \
        _Pragma("unroll")                                                               \
        for (int tt = 0; tt < 16; ++tt) {                                               \
            const unsigned kk_ = K[tt];                                                 \
            MN = kk_ < MN ? kk_ : MN;                                                   \
            const unsigned kf_ = (kk_ < INF_BITS) ? kk_ : 0u;                           \
            MX = kf_ > MX ? kf_ : MX;                                                   \
        }                                                                               \
        _Pragma("unroll")                                                               \
        for (int d = 1; d < 64; d <<= 1) {                                              \
            const unsigned omn = (unsigned)__shfl_xor((int)MN, d);                      \
            const unsigned omx = (unsigned)__shfl_xor((int)MX, d);                      \
            MN = omn < MN ? omn : MN;                                                   \
            MX = omx > MX ? omx : MX;                                                   \
        }                                                                               \
    }

// One bisection step for one row (stable when hi-lo<=1)
#define BISECT_STEP(K, LO, HI)                                                          \
    {                                                                                   \
        const unsigned mid_ = LO + ((HI - LO) >> 1);                                    \
        int cnt_ = 0;                                                                   \
        _Pragma("unroll")                                                               \
        for (int tt = 0; tt < 16; ++tt)                                                 \
            cnt_ += __popcll(__ballot(K[tt] < mid_));                                   \
        if (cnt_ >= 16) HI = mid_; else LO = mid_;                                      \
    }

// ---------------------------------------------------------------------------
// Boundary resolution for one row given V = 16th smallest f32 key.
// Fast path: no f32 tie ambiguity AND WINDOW gap -> f32 selection == f64's.
// Rare path: candidates one-per-lane, exact f64 rescore from nodes,
// (f64 bits, j) lowest-first extraction — jax top_k tie semantics.
// Uses lane, nbase, rowc, sqr64 from enclosing scope.
// ---------------------------------------------------------------------------
#define RESOLVE_ROW(K, V, RLOC, SELOUT)                                                 \
    {                                                                                   \
        const float Vw = __uint_as_float(V) + WINDOW;                                   \
        int cS = 0, nE = 0, cW = 0;                                                     \
        unsigned ltm = 0u, eqm = 0u, cm = 0u;                                           \
        _Pragma("unroll")                                                               \
        for (int tt = 0; tt < 16; ++tt) {                                               \
            const unsigned kk_ = K[tt];                                                 \
            const bool l_ = kk_ < (V);                                                  \
            const bool e_ = kk_ == (V);                                                 \
            const bool c_ = __uint_as_float(kk_) <= Vw;                                 \
            cS += __popcll(__ballot(l_));                                               \
            nE += __popcll(__ballot(e_));                                               \
            cW += __popcll(__ballot(c_));                                               \
            ltm |= (l_ ? 1u : 0u) << tt;                                                \
            eqm |= (e_ ? 1u : 0u) << tt;                                                \
            cm  |= (c_ ? 1u : 0u) << tt;                                                \
        }                                                                               \
        if (cS + nE == 16 && cW == 16) {                                                \
            SELOUT = ltm | eqm;                                                         \
        } else {                                                                        \
            int myj = -1;                                                               \
            {                                                                           \
                int cum = 0;                                                            \
                _Pragma("unroll")                                                       \
                for (int tt = 0; tt < 16; ++tt) {                                       \
                    const unsigned long long bm = __ballot((cm >> tt) & 1u);            \
                    const int pc = __popcll(bm);                                        \
                    if (myj < 0 && lane >= cum && lane < cum + pc) {                    \
                        unsigned long long mm = bm;                                     \
                        for (int z = lane - cum; z > 0; --z) mm &= mm - 1ull;           \
                        myj = tt * 64 + (__ffsll((unsigned long long)mm) - 1);          \
                    }                                                                   \
                    cum += pc;                                                          \
                }                                                                       \
            }                                                                           \
            unsigned long long dbits = ~0ull;                                           \
            if (myj >= 0) {                                                             \
                const float4* cp = (const float4*)(nbase + (size_t)myj * 64);           \
                double sq_ = 0.0, dt_ = 0.0;                                            \
                _Pragma("unroll")                                                       \
                for (int f = 0; f < 8; ++f) {                                           \
                    const float4 v = cp[f];                                             \
                    const float4 a = rowc[(RLOC) * 8 + f];                              \
                    sq_ = fma((double)v.x, (double)v.x, sq_);                           \
                    sq_ = fma((double)v.y, (double)v.y, sq_);                           \
                    sq_ = fma((double)v.z, (double)v.z, sq_);                           \
                    sq_ = fma((double)v.w, (double)v.w, sq_);                           \
                    dt_ = fma((double)v.x, (double)a.x, dt_);                           \
                    dt_ = fma((double)v.y, (double)a.y, dt_);                           \
                    dt_ = fma((double)v.z, (double)a.z, dt_);                           \
                    dt_ = fma((double)v.w, (double)a.w, dt_);                           \
                }                                                                       \
                double d64 = fma(-2.0, dt_, sqr64[RLOC] + sq_);                         \
                d64 = fmax(d64, (double)CLAMP_EPS);                                     \
                dbits = (unsigned long long)__double_as_longlong(d64);                  \
            }                                                                           \
            unsigned selb = 0u;                                                         \
            bool act = (myj >= 0);                                                      \
            for (int round = 0; round < 16; ++round) {                                  \
                unsigned long long best = act ? dbits : ~0ull;                          \
                _Pragma("unroll")                                                       \
                for (int d = 1; d < 64; d <<= 1)                                        \
                    best = ull_min(best,                                                \
                        (unsigned long long)__shfl_xor((long long)best, d));            \
                int pj = (act && dbits == best) ? myj : 0x7FFFFFFF;                     \
                _Pragma("unroll")                                                       \
                for (int d = 1; d < 64; d <<= 1) {                                      \
                    const int o = __shfl_xor(pj, d);                                    \
                    pj = o < pj ? o : pj;                                               \
                }                                                                       \
                if (myj == pj) act = false;                                             \
                if (lane == (pj & 63)) selb |= 1u << (pj >> 6);                         \
            }                                                                           \
            SELOUT = selb;                                                              \
        }                                                                               \
    }

// ---------------------------------------------------------------------------
// precompute: transpose coords into [b][f][j] float4 planes (coalesced main-
// loop loads) + per-column squared norms (identical fma order -> bitwise-
// identical keys). XCD-swizzled so batch b's panel is written by (and cached
// in the L2 of) the same XCD that later reads it: XCD x <-> batches [8x,8x+8).
// ---------------------------------------------------------------------------
__global__ __launch_bounds__(256) void transpose_norm_kernel(
    const float* __restrict__ nodes, float4* __restrict__ wsT,
    float* __restrict__ sqc)
{
    // 256 hw blocks; logical block l covers batch l/4. Map so l/32 == hw%8 (XCD id).
    const int w = blockIdx.x;
    const int l = (w & 7) * 32 + (w >> 3);
    const int g = l * 256 + threadIdx.x;             // 0..65535 = b*1024 + j
    const int b = g >> 10, j = g & 1023;
    const float4* cp = (const float4*)(nodes + (size_t)g * 64);
    float4 c[8];
    float s = 0.f;
#pragma unroll
    for (int f = 0; f < 8; ++f) {
        c[f] = cp[f];
        s = fmaf(c[f].x, c[f].x, s); s = fmaf(c[f].y, c[f].y, s);
        s = fmaf(c[f].z, c[f].z, s); s = fmaf(c[f].w, c[f].w, s);
    }
#pragma unroll
    for (int f = 0; f < 8; ++f)
        wsT[(((size_t)b * 8 + f) << 10) + j] = c[f];   // coalesced: consecutive j
    sqc[g] = s;
}

template <int USE_WS>
__global__ __launch_bounds__(64) void edge_knn_kernel(
    const float* __restrict__ nodes,
    const int*   __restrict__ mask,
    const float4* __restrict__ wsT,
    const float* __restrict__ sqcw,
    float*       __restrict__ out)
{
    const int lane = threadIdx.x;              // 64-thread blocks = 1 wave
    // XCD-aware bijective swizzle (nwg=16384, 16384%8==0): hw round-robins
    // XCDs, so give XCD x the contiguous logical range [x*2048,(x+1)*2048)
    // = batches [8x, 8x+8) -> per-XCD wsT working set 1MB, L2-resident.
    const int blk  = (int)((blockIdx.x & 7) * 2048 + (blockIdx.x >> 3));
    const int b    = blk >> 8;                 // 256 blocks per batch
    const int rowbase = (blk & 255) * 4;       // 4 rows per block

    const int* maskb = mask + b * NROW;
    float* edges = out + (size_t)b * NROW * NROW;
    float* adjm  = out + (size_t)64 * NROW * NROW + (size_t)b * NROW * NROW;

    // ---- fast path: all 4 rows masked -> zero-fill (d_out is poisoned)
    const int anyv = maskb[rowbase] | maskb[rowbase + 1] | maskb[rowbase + 2] | maskb[rowbase + 3];
    if (!anyv) {
        const nf4 z = {0.f, 0.f, 0.f, 0.f};
#pragma unroll
        for (int r = 0; r < 4; ++r) {
            nf4* e4 = reinterpret_cast<nf4*>(edges + (size_t)(rowbase + r) * NROW);
            nf4* a4 = reinterpret_cast<nf4*>(adjm  + (size_t)(rowbase + r) * NROW);
#pragma unroll
            for (int q = 0; q < 4; ++q) {
                __builtin_nontemporal_store(z, e4 + q * 64 + lane);
                __builtin_nontemporal_store(z, a4 + q * 64 + lane);
            }
        }
        return;
    }

    __shared__ float4 rowc[4 * 8];      // 512 B: this wave's 4 row coord vectors
    __shared__ float  sqr32s[4];
    __shared__ double sqr64[4];

    const float* nbase = nodes + (size_t)b * NROW * 64;

    if (lane < 32) {
        const int r = lane >> 3, f = lane & 7;
        rowc[lane] = ((const float4*)(nbase + (size_t)(rowbase + r) * 64))[f];
    }
    __syncthreads();
    if (lane < 4) {
        double s = 0.0;
#pragma unroll
        for (int f = 0; f < 8; ++f) {
            const float4 v = rowc[lane * 8 + f];
            s = fma((double)v.x, (double)v.x, s);
            s = fma((double)v.y, (double)v.y, s);
            s = fma((double)v.z, (double)v.z, s);
            s = fma((double)v.w, (double)v.w, s);
        }
        sqr64[lane] = s;
        sqr32s[lane] = (float)s;
    }
    __syncthreads();

    // column validity bits: bit tt <-> column j = tt*64 + lane
    unsigned mb = 0u;
#pragma unroll
    for (int tt = 0; tt < 16; ++tt)
        mb |= (maskb[tt * 64 + lane] != 0 ? 1u : 0u) << tt;

    const int row0 = rowbase;
    const bool rv0 = maskb[row0 + 0] != 0;
    const bool rv1 = maskb[row0 + 1] != 0;
    const bool rv2 = maskb[row0 + 2] != 0;
    const bool rv3 = maskb[row0 + 3] != 0;
    const float sqr0 = sqr32s[0], sqr1 = sqr32s[1];
    const float sqr2 = sqr32s[2], sqr3 = sqr32s[3];

    unsigned k0[16], k1[16], k2[16], k3[16];

    // ---- main loop: barrier-free; coalesced transposed loads (USE_WS)
#pragma unroll
    for (int tt = 0; tt < 16; ++tt) {
        if (__ballot((mb >> tt) & 1u) == 0ull) {   // wave-uniform prefix-mask skip
            k0[tt] = INF_BITS; k1[tt] = INF_BITS;
            k2[tt] = INF_BITS; k3[tt] = INF_BITS;
            continue;
        }
        const int j = tt * 64 + lane;
        float4 c[8];
        float sA;
        if (USE_WS) {
            const float4* tbase = wsT + ((size_t)b * 8 << 10);
#pragma unroll
            for (int f = 0; f < 8; ++f) c[f] = tbase[(f << 10) + j];
            sA = sqcw[(size_t)b * NROW + j];       // coalesced dword, L2-hot
        } else {
            const float4* cp = (const float4*)(nbase + (size_t)j * 64);
#pragma unroll
            for (int f = 0; f < 8; ++f) c[f] = cp[f];
            sA = 0.f;
#pragma unroll
            for (int f = 0; f < 8; ++f) {
                sA = fmaf(c[f].x, c[f].x, sA); sA = fmaf(c[f].y, c[f].y, sA);
                sA = fmaf(c[f].z, c[f].z, sA); sA = fmaf(c[f].w, c[f].w, sA);
            }
        }

        float d0 = 0.f, d1 = 0.f, d2 = 0.f, d3 = 0.f;
#pragma unroll
        for (int f = 0; f < 8; ++f) {
            const float4 v  = c[f];
            const float4 a0 = rowc[0 * 8 + f];   // wave-uniform broadcast reads
            const float4 a1 = rowc[1 * 8 + f];
            const float4 a2 = rowc[2 * 8 + f];
            const float4 a3 = rowc[3 * 8 + f];
            d0 = fmaf(v.x, a0.x, d0); d0 = fmaf(v.y, a0.y, d0);
            d0 = fmaf(v.z, a0.z, d0); d0 = fmaf(v.w, a0.w, d0);
            d1 = fmaf(v.x, a1.x, d1); d1 = fmaf(v.y, a1.y, d1);
            d1 = fmaf(v.z, a1.z, d1); d1 = fmaf(v.w, a1.w, d1);
            d2 = fmaf(v.x, a2.x, d2); d2 = fmaf(v.y, a2.y, d2);
            d2 = fmaf(v.z, a2.z, d2); d2 = fmaf(v.w, a2.w, d2);
            d3 = fmaf(v.x, a3.x, d3); d3 = fmaf(v.y, a3.y, d3);
            d3 = fmaf(v.z, a3.z, d3); d3 = fmaf(v.w, a3.w, d3);
        }

        const bool cv = (mb >> tt) & 1u;
        float e_;
        e_ = fmaxf(fmaf(-2.f, d0, sqr0 + sA), CLAMP_EPS);
        k0[tt] = (cv && j != row0 + 0) ? __float_as_uint(e_) : INF_BITS;
        e_ = fmaxf(fmaf(-2.f, d1, sqr1 + sA), CLAMP_EPS);
        k1[tt] = (cv && j != row0 + 1) ? __float_as_uint(e_) : INF_BITS;
        e_ = fmaxf(fmaf(-2.f, d2, sqr2 + sA), CLAMP_EPS);
        k2[tt] = (cv && j != row0 + 2) ? __float_as_uint(e_) : INF_BITS;
        e_ = fmaxf(fmaf(-2.f, d3, sqr3 + sA), CLAMP_EPS);
        k3[tt] = (cv && j != row0 + 3) ? __float_as_uint(e_) : INF_BITS;
    }

    // ---- joint 4-row bisection (4 independent ballot chains per iteration)
    unsigned mn0, mx0, mn1, mx1, mn2, mx2, mn3, mx3;
    ROW_MINMAX(k0, mn0, mx0);
    ROW_MINMAX(k1, mn1, mx1);
    ROW_MINMAX(k2, mn2, mx2);
    ROW_MINMAX(k3, mn3, mx3);

    unsigned lo0 = mn0, hi0 = mx0 + 1u;
    unsigned lo1 = mn1, hi1 = mx1 + 1u;
    unsigned lo2 = mn2, hi2 = mx2 + 1u;
    unsigned lo3 = mn3, hi3 = mx3 + 1u;
    if (!rv0) { lo0 = 0u; hi0 = 1u; }
    if (!rv1) { lo1 = 0u; hi1 = 1u; }
    if (!rv2) { lo2 = 0u; hi2 = 1u; }
    if (!rv3) { lo3 = 0u; hi3 = 1u; }

    for (;;) {
        const unsigned dm = umax2(umax2(hi0 - lo0, hi1 - lo1), umax2(hi2 - lo2, hi3 - lo3));
        if (dm <= 1u) break;
        BISECT_STEP(k0, lo0, hi0);
        BISECT_STEP(k1, lo1, hi1);
        BISECT_STEP(k2, lo2, hi2);
        BISECT_STEP(k3, lo3, hi3);
    }

    // ---- boundary resolution (wave-uniform per-row branches)
    unsigned sel0 = 0u, sel1 = 0u, sel2 = 0u, sel3 = 0u;
    if (rv0) RESOLVE_ROW(k0, lo0, 0, sel0);
    if (rv1) RESOLVE_ROW(k1, lo1, 1, sel1);
    if (rv2) RESOLVE_ROW(k2, lo2, 2, sel2);
    if (rv3) RESOLVE_ROW(k3, lo3, 3, sel3);

    // ---- dense output (coalesced NT dword streams; bypass L2 so the 537MB
    // write stream doesn't evict the XCD-local wsT panels — r16 A/B evidence)
#pragma unroll
    for (int tt = 0; tt < 16; ++tt) {
        const int j = tt * 64 + lane;
        {
            const bool s = (sel0 >> tt) & 1u;
            __builtin_nontemporal_store(s ? sqrtf(__uint_as_float(k0[tt])) : 0.f,
                                        edges + (size_t)(row0 + 0) * NROW + j);
            __builtin_nontemporal_store(s ? 1.f : 0.f,
                                        adjm + (size_t)(row0 + 0) * NROW + j);
        }
        {
            const bool s = (sel1 >> tt) & 1u;
            __builtin_nontemporal_store(s ? sqrtf(__uint_as_float(k1[tt])) : 0.f,
                                        edges + (size_t)(row0 + 1) * NROW + j);
            __builtin_nontemporal_store(s ? 1.f : 0.f,
                                        adjm + (size_t)(row0 + 1) * NROW + j);
        }
        {
            const bool s = (sel2 >> tt) & 1u;
            __builtin_nontemporal_store(s ? sqrtf(__uint_as_float(k2[tt])) : 0.f,
                                        edges + (size_t)(row0 + 2) * NROW + j);
            __builtin_nontemporal_store(s ? 1.f : 0.f,
                                        adjm + (size_t)(row0 + 2) * NROW + j);
        }
        {
            const bool s = (sel3 >> tt) & 1u;
            __builtin_nontemporal_store(s ? sqrtf(__uint_as_float(k3[tt])) : 0.f,
                                        edges + (size_t)(row0 + 3) * NROW + j);
            __builtin_nontemporal_store(s ? 1.f : 0.f,
                                        adjm + (size_t)(row0 + 3) * NROW + j);
        }
    }
}

extern "C" void kernel_launch(void* const* d_in, const int* in_sizes, int n_in,
                              void* d_out, int out_size, void* d_ws, size_t ws_size,
                              hipStream_t stream)
{
    const float* nodes = (const float*)d_in[0];
    const int*   mask  = (const int*)d_in[1];
    float* out = (float*)d_out;

    dim3 grid(64 * 256);   // 64 batches x 256 blocks (4 rows each, 1 wave/block)
    dim3 block(64);

    const size_t wsT_f4 = (size_t)64 * 8 * 1024;              // 8 MB of float4
    const size_t need   = wsT_f4 * sizeof(float4) + (size_t)64 * NROW * sizeof(float);
    const bool   use_ws = ws_size >= need;

    if (use_ws) {
        float4* wsT = (float4*)d_ws;
        float*  sqc = (float*)((char*)d_ws + wsT_f4 * sizeof(float4));
        hipLaunchKernelGGL(transpose_norm_kernel, dim3(64 * NROW / 256), dim3(256), 0, stream,
                           nodes, wsT, sqc);
        hipLaunchKernelGGL((edge_knn_kernel<1>), grid, block, 0, stream,
                           nodes, mask, (const float4*)wsT, (const float*)sqc, out);
    } else {
        hipLaunchKernelGGL((edge_knn_kernel<0>), grid, block, 0, stream,
                           nodes, mask, (const float4*)nullptr, (const float*)nullptr, out);
    }
}